// Round 1
// baseline (143.148 us; speedup 1.0000x reference)
//
#include <hip/hip_runtime.h>
#include <hip/hip_bf16.h>
#include <math.h>

// Problem constants (from reference setup_inputs)
#define NPTS   65536
#define NGT    256
#define NCLS   80
#define TOPK   9
#define B1     512    // stage-1 blocks
#define PPB    128    // points per stage-1 block (B1*PPB == NPTS)

// ---------------------------------------------------------------------------
// Stage 0: zero the output (harness poisons d_out with 0xAA before each call)
// ---------------------------------------------------------------------------
__global__ void zero_out_kernel(float* __restrict__ w, int n) {
    int i = blockIdx.x * 256 + threadIdx.x;
    if (i < n) w[i] = 0.0f;
}

// ---------------------------------------------------------------------------
// Stage 1: per (gt, point-chunk) top-9 by score rank.
// Rank key: L = (1-ALPHA)*log2(sigmoid(cls)) + ALPHA*log2(iou)  (monotone in
// the reference score  sigmoid^.2 * iou^.8 ; iou==0 -> constant -1e30 so the
// tie structure among zero-score points matches the reference exactly).
// One thread per gt; block stages PPB points' bbox + 0.2*log2(sigmoid) for
// all 80 classes in LDS (cls_scores read once, coalesced).
// Output: cand[g][b][k] = packed u64 (sortable_float_bits<<32) | ~point_idx
// so that u64-max == (higher score, then lower index) — JAX top_k tie-break.
// ---------------------------------------------------------------------------
__global__ __launch_bounds__(256) void stage1_kernel(
    const float* __restrict__ cls,     // [NPTS][NCLS]
    const float* __restrict__ preds,   // [NPTS][4]
    const float* __restrict__ gtb,     // [NGT][4]
    const int*   __restrict__ glab,    // [NGT]
    unsigned long long* __restrict__ cand) // [NGT][B1][TOPK]
{
    __shared__ float  lsig[PPB][NCLS + 1]; // +1 pad: LDS bank spread
    __shared__ float4 pbox[PPB];

    const int b    = blockIdx.x;
    const int t    = threadIdx.x;     // = gt index
    const int base = b * PPB;

    const float E1 = 1.0f - 0.8f;     // same constant expr as reference

    // --- stage cls rows (coalesced, read exactly once grid-wide) ---
    for (int i = t; i < PPB * NCLS; i += 256) {
        int p = i / NCLS;
        int c = i - p * NCLS;
        float x = cls[(size_t)(base + p) * NCLS + c];
        float s = 1.0f / (1.0f + expf(-x));
        lsig[p][c] = E1 * log2f(s);
    }
    // --- stage bboxes ---
    if (t < PPB) pbox[t] = ((const float4*)preds)[base + t];

    // --- per-thread gt data ---
    float4 g4  = ((const float4*)gtb)[t];
    int    lab = glab[t];
    float  garea = (g4.z - g4.x) * (g4.w - g4.y);
    __syncthreads();

    // --- register-resident sorted (desc) top-9 ---
    float    vals[TOPK];
    unsigned idxs[TOPK];
#pragma unroll
    for (int k = 0; k < TOPK; ++k) { vals[k] = -INFINITY; idxs[k] = 0u; }

    for (int p = 0; p < PPB; ++p) {
        float4 pb = pbox[p];                    // LDS broadcast (uniform addr)
        float ix1 = fmaxf(pb.x, g4.x), iy1 = fmaxf(pb.y, g4.y);
        float ix2 = fminf(pb.z, g4.z), iy2 = fminf(pb.w, g4.w);
        float iw  = fmaxf(ix2 - ix1, 0.0f);
        float ih  = fmaxf(iy2 - iy1, 0.0f);
        float inter = iw * ih;
        float L;
        if (inter > 0.0f) {
            float parea = (pb.z - pb.x) * (pb.w - pb.y);
            float uni   = fmaxf(parea + garea - inter, 1e-6f);
            float iou   = inter / uni;
            L = lsig[p][lab] + 0.8f * log2f(iou);
        } else {
            L = -1e30f;   // all zero-score points identical => index tie-break
        }
        if (L > vals[TOPK - 1]) {               // strict: earlier index wins ties
            vals[TOPK - 1] = L;
            idxs[TOPK - 1] = (unsigned)(base + p);
#pragma unroll
            for (int k = TOPK - 1; k > 0; --k) {
                if (vals[k] > vals[k - 1]) {    // strict: stable among equals
                    float    tv = vals[k]; vals[k] = vals[k - 1]; vals[k - 1] = tv;
                    unsigned ti = idxs[k]; idxs[k] = idxs[k - 1]; idxs[k - 1] = ti;
                }
            }
        }
    }

    // --- emit packed keys (list is desc by key) ---
#pragma unroll
    for (int k = 0; k < TOPK; ++k) {
        unsigned u   = __float_as_uint(vals[k]);
        unsigned k32 = (u & 0x80000000u) ? ~u : (u | 0x80000000u); // sortable
        cand[((size_t)t * B1 + b) * TOPK + k] =
            ((unsigned long long)k32 << 32) | (unsigned)(~idxs[k]);
    }
}

// ---------------------------------------------------------------------------
// Stage 2+3: per gt, merge B1 sorted lists -> global top-9, then the 9-point
// Gaussian weight + validity + scatter-max (atomicMax on int bits; weights
// are >= 0 and w pre-zeroed so int ordering == float ordering).
// ---------------------------------------------------------------------------
__global__ __launch_bounds__(256) void stage2_kernel(
    const unsigned long long* __restrict__ cand, // [NGT][B1][TOPK]
    const float* __restrict__ pts,               // [NPTS][2]
    const float* __restrict__ gtb,               // [NGT][4]
    float* __restrict__ w)                       // [NPTS]
{
    const int g = blockIdx.x;
    const int t = threadIdx.x;

    __shared__ unsigned long long lc[B1 * TOPK];  // 36 KiB
    __shared__ unsigned long long red[256];
    __shared__ unsigned top_idx[TOPK];
    __shared__ float ppy[TOPK], ppx[TOPK];

    // coalesced load of this gt's candidate block
    const unsigned long long* src = cand + (size_t)g * (B1 * TOPK);
    for (int i = t; i < B1 * TOPK; i += 256) lc[i] = src[i];
    __syncthreads();

    // each thread merges two sorted-desc lists (2t, 2t+1) -> local top-9
    unsigned long long loc[TOPK];
#pragma unroll
    for (int k = 0; k < TOPK; ++k) loc[k] = lc[(2 * t) * TOPK + k];
#pragma unroll
    for (int k = 0; k < TOPK; ++k) {
        unsigned long long v = lc[(2 * t + 1) * TOPK + k];
        if (v > loc[TOPK - 1]) {
            loc[TOPK - 1] = v;
#pragma unroll
            for (int j = TOPK - 1; j > 0; --j) {
                if (loc[j] > loc[j - 1]) {
                    unsigned long long tmp = loc[j];
                    loc[j] = loc[j - 1]; loc[j - 1] = tmp;
                }
            }
        }
    }

    // 9 rounds of block-argmax; keys are unique per gt (disjoint point ranges)
    int pos = 0;
    for (int r = 0; r < TOPK; ++r) {
        red[t] = (pos < TOPK) ? loc[pos] : 0ULL;
        __syncthreads();
        for (int s = 128; s > 0; s >>= 1) {
            if (t < s) {
                unsigned long long o = red[t + s];
                if (o > red[t]) red[t] = o;
            }
            __syncthreads();
        }
        unsigned long long win = red[0];
        __syncthreads();                 // everyone read win before red reuse
        if (pos < TOPK && loc[pos] == win) ++pos;   // unique winner pops
        if (t == 0) top_idx[r] = ~(unsigned)(win & 0xFFFFFFFFu);
    }
    __syncthreads();

    // parallel prefetch of the 9 candidate points
    if (t < TOPK) {
        unsigned pi = top_idx[t];
        ppy[t] = pts[2 * (size_t)pi];       // points col 0 -> "cy" in reference
        ppx[t] = pts[2 * (size_t)pi + 1];   // points col 1 -> "cx"
    }
    __syncthreads();

    if (t == 0) {
        float4 g4 = ((const float4*)gtb)[g];
        float m0 = 0.0f, m1 = 0.0f;
#pragma unroll
        for (int k = 0; k < TOPK; ++k) { m0 += ppy[k]; m1 += ppx[k]; }
        m0 /= (float)TOPK; m1 /= (float)TOPK;

        float d0[TOPK], d1[TOPK];
        float a = 0.0f, bb = 0.0f, dd = 0.0f;
#pragma unroll
        for (int k = 0; k < TOPK; ++k) {
            d0[k] = ppy[k] - m0;
            d1[k] = ppx[k] - m1;
            a  += d0[k] * d0[k];
            bb += d0[k] * d1[k];
            dd += d1[k] * d1[k];
        }
        a /= (float)TOPK; bb /= (float)TOPK; dd /= (float)TOPK;
        float det  = a * dd - bb * bb;
        float rinv = 1.0f / (det + 1e-10f);

#pragma unroll
        for (int k = 0; k < TOPK; ++k) {
            // diff . (adj(sigma)/ (det+eps)) . diff
            float q = d0[k] * (dd * d0[k] - bb * d1[k])
                    + d1[k] * (a  * d1[k] - bb * d0[k]);
            float maha = q * rinv;
            float wt = expf(-0.5f * maha);
            bool valid = (ppx[k] - g4.x > 1e-10f) && (ppy[k] - g4.y > 1e-10f) &&
                         (g4.z - ppx[k] > 1e-10f) && (g4.w - ppy[k] > 1e-10f);
            float wv = valid ? wt : 0.0f;
            atomicMax((int*)&w[top_idx[k]], __float_as_int(wv));
        }
    }
}

// ---------------------------------------------------------------------------
extern "C" void kernel_launch(void* const* d_in, const int* in_sizes, int n_in,
                              void* d_out, int out_size, void* d_ws, size_t ws_size,
                              hipStream_t stream) {
    const float* points  = (const float*)d_in[0];   // [65536,2]
    const float* cls     = (const float*)d_in[1];   // [65536,80]
    const float* preds   = (const float*)d_in[2];   // [65536,4]
    const float* gtb     = (const float*)d_in[3];   // [256,4]
    const int*   glab    = (const int*)d_in[4];     // [256]
    float* w = (float*)d_out;                       // [65536] f32

    unsigned long long* cand = (unsigned long long*)d_ws; // 256*512*9*8 = 9.44 MB

    zero_out_kernel<<<(NPTS + 255) / 256, 256, 0, stream>>>(w, NPTS);
    stage1_kernel<<<B1, 256, 0, stream>>>(cls, preds, gtb, glab, cand);
    stage2_kernel<<<NGT, 256, 0, stream>>>(cand, points, gtb, w);
}